// Round 9
// baseline (468.605 us; speedup 1.0000x reference)
//
#include <hip/hip_runtime.h>
#include <hip/hip_bf16.h>
#include <math.h>

// Problem constants: B=4, S=2048, D=256, H=8, DK=32, L=4, FF=512
#define SEQ 2048
#define DIM 256
#define NH 8
#define DK 32
#define FF 512

typedef __bf16 bf16_t;
typedef bf16_t bf16x8 __attribute__((ext_vector_type(8)));
typedef bf16_t bf16x4 __attribute__((ext_vector_type(4)));
typedef float f32x4 __attribute__((ext_vector_type(4)));

// Q pre-scaled by (1/sqrt(DK)) * log2(e); softmax exp becomes v_exp_f32 (2^x).
#define QK_SCALE_LOG2 0.25503226632462494f
#if __has_builtin(__builtin_amdgcn_exp2f)
#define FAST_EXP2(x) __builtin_amdgcn_exp2f(x)
#else
#define FAST_EXP2(x) __expf((x) * 0.6931471805599453f)
#endif

// ---------------------------------------------------------------------------
// LayerNorm: one wave per row of 256 floats. OUT_BF=0 -> fp32, 1 -> bf16.
// ---------------------------------------------------------------------------
template <int OUT_BF>
__global__ __launch_bounds__(256) void ln_kernel(
    const float* __restrict__ x, const float* __restrict__ s,
    const float* __restrict__ b, float* __restrict__ outf,
    bf16_t* __restrict__ outb) {
  int wave = threadIdx.x >> 6;
  int lane = threadIdx.x & 63;
  int row = blockIdx.x * 4 + wave;
  const float* xr = x + (size_t)row * DIM + lane * 4;
  float4 xv = *(const float4*)xr;
  float sum = xv.x + xv.y + xv.z + xv.w;
  float sq = xv.x * xv.x + xv.y * xv.y + xv.z * xv.z + xv.w * xv.w;
#pragma unroll
  for (int off = 1; off < 64; off <<= 1) {
    sum += __shfl_xor(sum, off);
    sq += __shfl_xor(sq, off);
  }
  float mean = sum * (1.0f / 256.0f);
  float var = sq * (1.0f / 256.0f) - mean * mean;
  float inv = rsqrtf(var + 1e-5f);
  float4 sv = *(const float4*)(s + lane * 4);
  float4 bv = *(const float4*)(b + lane * 4);
  float4 o;
  o.x = (xv.x - mean) * inv * sv.x + bv.x;
  o.y = (xv.y - mean) * inv * sv.y + bv.y;
  o.z = (xv.z - mean) * inv * sv.z + bv.z;
  o.w = (xv.w - mean) * inv * sv.w + bv.w;
  if (OUT_BF) {
    bf16x4 ob = {(bf16_t)o.x, (bf16_t)o.y, (bf16_t)o.z, (bf16_t)o.w};
    *(bf16x4*)(outb + (size_t)row * DIM + lane * 4) = ob;
  } else {
    *(float4*)(outf + (size_t)row * DIM + lane * 4) = o;
  }
}

// ---------------------------------------------------------------------------
// All-weights transpose+convert in ONE dispatch (512 blocks).
// in f32 [K][N] -> out bf16 [N][K].
// ---------------------------------------------------------------------------
__global__ __launch_bounds__(256) void wtrans_all_kernel(
    const float* __restrict__ wq, const float* __restrict__ wk,
    const float* __restrict__ wv, const float* __restrict__ wo,
    const float* __restrict__ w1, const float* __restrict__ w2,
    bf16_t* __restrict__ WqT, bf16_t* __restrict__ WkT,
    bf16_t* __restrict__ WvT, bf16_t* __restrict__ WoT,
    bf16_t* __restrict__ W1T, bf16_t* __restrict__ W2T) {
  __shared__ float tile[64][65];
  int idx = blockIdx.x;
  int layer = idx >> 7;
  int r = idx & 127;
  const float* src;
  bf16_t* dst;
  int N, k0, n0;
  if (r < 64) {
    int which = r >> 4, t = r & 15;
    N = 256;
    k0 = (t & 3) * 64;
    n0 = (t >> 2) * 64;
    src = (which == 0 ? wq : which == 1 ? wk : which == 2 ? wv : wo) + (size_t)layer * 65536;
    dst = (which == 0 ? WqT : which == 1 ? WkT : which == 2 ? WvT : WoT) + (size_t)layer * 65536;
  } else if (r < 96) {
    int t = r - 64;
    N = 512;
    k0 = (t & 3) * 64;
    n0 = (t >> 2) * 64;
    src = w1 + (size_t)layer * 131072;
    dst = W1T + (size_t)layer * 131072;
  } else {
    int t = r - 96;
    N = 256;
    k0 = (t & 7) * 64;
    n0 = (t >> 3) * 64;
    src = w2 + (size_t)layer * 131072;
    dst = W2T + (size_t)layer * 131072;
  }
  int K = (r >= 96) ? 512 : 256;

  int tr = threadIdx.x >> 4;
  int tc4 = (threadIdx.x & 15) * 4;
#pragma unroll
  for (int i = 0; i < 4; i++) {
    int kl = i * 16 + tr;
    float4 v = *(const float4*)(src + (size_t)(k0 + kl) * N + n0 + tc4);
    tile[kl][tc4 + 0] = v.x; tile[kl][tc4 + 1] = v.y;
    tile[kl][tc4 + 2] = v.z; tile[kl][tc4 + 3] = v.w;
  }
  __syncthreads();
#pragma unroll
  for (int i = 0; i < 4; i++) {
    int nl = i * 16 + tr;
    bf16x4 o = {(bf16_t)tile[tc4 + 0][nl], (bf16_t)tile[tc4 + 1][nl],
                (bf16_t)tile[tc4 + 2][nl], (bf16_t)tile[tc4 + 3][nl]};
    *(bf16x4*)(dst + (size_t)(n0 + nl) * K + k0 + tc4) = o;
  }
}

// ---------------------------------------------------------------------------
// m97-style 128x128 GEMM core. 256 threads = 4 waves in 2x2, wave tile 64x64
// (4x4 MFMA 16x16x32, 64 acc VGPRs). BK=64 double-buffered LDS staged via
// global_load_lds width=16 with XOR chunk swizzle (conflict-reduced b128
// reads). A [M][K] bf16 row-major, BT [N][K] bf16 row-major.
// ---------------------------------------------------------------------------
__device__ __forceinline__ void stage128(const bf16_t* __restrict__ src,
                                         bf16_t* dst, int tid, int ldk, int k0) {
  // 128 rows x 64 k = 16 KB = 1024 chunks of 16 B; 256 threads x 4 issues.
#pragma unroll
  for (int u = 0; u < 4; u++) {
    int i = u * 256 + tid;
    int m = i >> 3, cd = i & 7, cs = cd ^ (m & 7);
    const bf16_t* g = src + (size_t)m * ldk + k0 + cs * 8;
    __builtin_amdgcn_global_load_lds(
        (const __attribute__((address_space(1))) unsigned int*)g,
        (__attribute__((address_space(3))) unsigned int*)(dst + i * 8),
        16, 0, 0);
  }
}

__device__ __forceinline__ void compute128(const bf16_t* As, const bf16_t* Bs,
                                           int wr, int wc, int n16, int quad,
                                           f32x4 (&acc)[4][4]) {
#pragma unroll
  for (int ks = 0; ks < 2; ks++) {
    bf16x8 af[4], bf[4];
#pragma unroll
    for (int mt = 0; mt < 4; mt++) {
      int row = wr * 64 + mt * 16 + n16;
      int cd = (ks * 4 + quad) ^ (row & 7);
      af[mt] = *(const bf16x8*)(As + row * 64 + cd * 8);
    }
#pragma unroll
    for (int nt = 0; nt < 4; nt++) {
      int row = wc * 64 + nt * 16 + n16;
      int cd = (ks * 4 + quad) ^ (row & 7);
      bf[nt] = *(const bf16x8*)(Bs + row * 64 + cd * 8);
    }
#pragma unroll
    for (int mt = 0; mt < 4; mt++)
#pragma unroll
      for (int nt = 0; nt < 4; nt++)
        acc[mt][nt] = __builtin_amdgcn_mfma_f32_16x16x32_bf16(
            af[mt], bf[nt], acc[mt][nt], 0, 0, 0);
  }
}

template <int K>
__device__ __forceinline__ void gemm9_body(
    const bf16_t* __restrict__ A, const bf16_t* __restrict__ BT,
    int m0, int n0, int tid, bf16_t* As, bf16_t* Bs, f32x4 (&acc)[4][4]) {
  int lane = tid & 63;
  int n16 = lane & 15, quad = lane >> 4;
  int w = tid >> 6;
  int wr = w >> 1, wc = w & 1;
  const bf16_t* Arow = A + (size_t)m0 * K;
  const bf16_t* Brow = BT + (size_t)n0 * K;

  stage128(Arow, As, tid, K, 0);
  stage128(Brow, Bs, tid, K, 0);

  const int steps = K / 64;
#pragma unroll
  for (int s = 0; s < steps; s++) {
    int buf = s & 1;
    if (s + 1 < steps) {
      stage128(Arow, As + (buf ^ 1) * 8192, tid, K, (s + 1) * 64);
      stage128(Brow, Bs + (buf ^ 1) * 8192, tid, K, (s + 1) * 64);
    }
    __syncthreads();  // drain staging of buf (and prefetch) before reading
    compute128(As + buf * 8192, Bs + buf * 8192, wr, wc, n16, quad, acc);
    if (s + 2 < steps) __syncthreads();  // reads of buf done before restage
  }
}

// ---------------------------------------------------------------------------
// Generic 128x128 GEMM. MODE 0: fp32 residual add. MODE 1: bf16 relu.
// ---------------------------------------------------------------------------
template <int MODE, int N, int K>
__global__ __launch_bounds__(256) void gemm9_kernel(
    const bf16_t* __restrict__ A, const bf16_t* __restrict__ BT,
    const float* __restrict__ bias, const float* __restrict__ resid,
    float* __restrict__ outf, bf16_t* __restrict__ outb) {
  __shared__ __align__(16) bf16_t As[2 * 8192];
  __shared__ __align__(16) bf16_t Bs[2 * 8192];
  int tid = threadIdx.x;
  int lane = tid & 63;
  int n16 = lane & 15, quad = lane >> 4;
  int w = tid >> 6;
  int wr = w >> 1, wc = w & 1;
  int m0 = blockIdx.y * 128, n0 = blockIdx.x * 128;
  f32x4 acc[4][4] = {};
  gemm9_body<K>(A, BT, m0, n0, tid, As, Bs, acc);

#pragma unroll
  for (int nt = 0; nt < 4; nt++) {
    int n = n0 + wc * 64 + nt * 16 + n16;
    float bv = bias[n];
#pragma unroll
    for (int mt = 0; mt < 4; mt++) {
#pragma unroll
      for (int r = 0; r < 4; r++) {
        int m = m0 + wr * 64 + mt * 16 + quad * 4 + r;
        float val = acc[mt][nt][r] + bv;
        if (MODE == 0) {
          size_t idx = (size_t)m * N + n;
          outf[idx] = resid[idx] + val;
        } else {
          outb[(size_t)m * N + n] = (bf16_t)fmaxf(val, 0.0f);
        }
      }
    }
  }
}

// ---------------------------------------------------------------------------
// Fused QKV projection on the 128x128 body: grid (6, 64).
// blockIdx.x: which = x>>1 (Q/K/V), nblk = x&1.
// Q -> bf16 [B,H,S,DK] * QK_SCALE_LOG2; K -> bf16 [B,H,S,DK];
// V -> bf16 [B,H,DK,S] (transposed, bf16x4 packed over s).
// ---------------------------------------------------------------------------
__global__ __launch_bounds__(256) void qkv9_kernel(
    const bf16_t* __restrict__ A,
    const bf16_t* __restrict__ WqT, const bf16_t* __restrict__ WkT,
    const bf16_t* __restrict__ WvT,
    const float* __restrict__ bq, const float* __restrict__ bk,
    const float* __restrict__ bv,
    bf16_t* __restrict__ qo, bf16_t* __restrict__ ko,
    bf16_t* __restrict__ vo) {
  __shared__ __align__(16) bf16_t As[2 * 8192];
  __shared__ __align__(16) bf16_t Bs[2 * 8192];
  int which = blockIdx.x >> 1;
  int nblk = blockIdx.x & 1;
  const bf16_t* BT = (which == 0) ? WqT : (which == 1) ? WkT : WvT;
  const float* bias = (which == 0) ? bq : (which == 1) ? bk : bv;

  int tid = threadIdx.x;
  int lane = tid & 63;
  int n16 = lane & 15, quad = lane >> 4;
  int w = tid >> 6;
  int wr = w >> 1, wc = w & 1;
  int m0 = blockIdx.y * 128, n0 = nblk * 128;
  f32x4 acc[4][4] = {};
  gemm9_body<256>(A, BT, m0, n0, tid, As, Bs, acc);

#pragma unroll
  for (int nt = 0; nt < 4; nt++) {
    int n = n0 + wc * 64 + nt * 16 + n16;
    float bv_ = bias[n];
    int hh = n >> 5, dk = n & 31;
#pragma unroll
    for (int mt = 0; mt < 4; mt++) {
      if (which == 2) {
        int s0 = m0 + wr * 64 + mt * 16 + quad * 4;
        int bb = s0 >> 11, ss0 = s0 & 2047;
        bf16x4 o;
#pragma unroll
        for (int r = 0; r < 4; r++) o[r] = (bf16_t)(acc[mt][nt][r] + bv_);
        *(bf16x4*)(vo + ((size_t)(bb * NH + hh) * DK + dk) * SEQ + ss0) = o;
      } else {
        bf16_t* dst = (which == 0) ? qo : ko;
        float sc = (which == 0) ? QK_SCALE_LOG2 : 1.0f;
#pragma unroll
        for (int r = 0; r < 4; r++) {
          int m = m0 + wr * 64 + mt * 16 + quad * 4 + r;
          int bb = m >> 11, ss = m & 2047;
          dst[((size_t)(bb * NH + hh) * SEQ + ss) * DK + dk] =
              (bf16_t)((acc[mt][nt][r] + bv_) * sc);
        }
      }
    }
  }
}

// ---------------------------------------------------------------------------
// Flash attention v7 (unchanged from R7): 32 q/wave, S^T score trick,
// ones-MFMA row-sums, double-buffered P LDS, register K/V prefetch.
// grid (32 bh, 32 qblk), 128 threads.
// ---------------------------------------------------------------------------
__global__ __launch_bounds__(128) void flash7_kernel(
    const bf16_t* __restrict__ Q, const bf16_t* __restrict__ K,
    const bf16_t* __restrict__ VT, bf16_t* __restrict__ OB) {
  __shared__ __align__(16) bf16_t Plds[2][2][32][72];
  int bh = blockIdx.x;
  int q0 = blockIdx.y * 64;
  int w = threadIdx.x >> 6;
  int lane = threadIdx.x & 63;
  int n16 = lane & 15;
  int quad = lane >> 4;

  const bf16_t* Qb = Q + (size_t)bh * SEQ * DK;
  const bf16_t* Kb = K + (size_t)bh * SEQ * DK;
  const bf16_t* Vb = VT + (size_t)bh * DK * SEQ;
  int qr0 = q0 + w * 32;

  bf16x8 qfrag[2];
#pragma unroll
  for (int qg = 0; qg < 2; qg++)
    qfrag[qg] = *(const bf16x8*)(Qb + (size_t)(qr0 + qg * 16 + n16) * DK + quad * 8);

  bf16_t one = (bf16_t)1.0f;
  bf16x8 ones = {one, one, one, one, one, one, one, one};

  f32x4 oacc[2][2] = {};
  f32x4 lacc[2] = {};

  bf16x8 kfc[4], vfc[2][2];
#pragma unroll
  for (int t = 0; t < 4; t++)
    kfc[t] = *(const bf16x8*)(Kb + (size_t)(t * 16 + n16) * DK + quad * 8);
#pragma unroll
  for (int c = 0; c < 2; c++) {
    vfc[c][0] = *(const bf16x8*)(Vb + (size_t)n16 * SEQ + c * 32 + quad * 8);
    vfc[c][1] = *(const bf16x8*)(Vb + (size_t)(16 + n16) * SEQ + c * 32 + quad * 8);
  }

#pragma unroll 2
  for (int kb0 = 0; kb0 < SEQ; kb0 += 64) {
    int buf = (kb0 >> 6) & 1;
    int nb = kb0 + 64;
    bool has_next = nb < SEQ;
    bf16x8 kfn[4], vfn[2][2];
    if (has_next) {
#pragma unroll
      for (int t = 0; t < 4; t++)
        kfn[t] = *(const bf16x8*)(Kb + (size_t)(nb + t * 16 + n16) * DK + quad * 8);
#pragma unroll
      for (int c = 0; c < 2; c++) {
        vfn[c][0] = *(const bf16x8*)(Vb + (size_t)n16 * SEQ + nb + c * 32 + quad * 8);
        vfn[c][1] = *(const bf16x8*)(Vb + (size_t)(16 + n16) * SEQ + nb + c * 32 + quad * 8);
      }
    }
#pragma unroll
    for (int qg = 0; qg < 2; qg++) {
#pragma unroll
      for (int t = 0; t < 4; t++) {
        f32x4 sc = __builtin_amdgcn_mfma_f32_16x16x32_bf16(
            kfc[t], qfrag[qg], (f32x4){0.f, 0.f, 0.f, 0.f}, 0, 0, 0);
        bf16x4 pf;
#pragma unroll
        for (int r = 0; r < 4; r++) pf[r] = (bf16_t)FAST_EXP2(sc[r]);
        *(bf16x4*)&Plds[buf][w][qg * 16 + n16][t * 16 + quad * 4] = pf;
      }
    }
#pragma unroll
    for (int qg = 0; qg < 2; qg++)
#pragma unroll
      for (int c = 0; c < 2; c++) {
        bf16x8 pf8 = *(const bf16x8*)&Plds[buf][w][qg * 16 + n16][c * 32 + quad * 8];
        lacc[qg] = __builtin_amdgcn_mfma_f32_16x16x32_bf16(pf8, ones, lacc[qg], 0, 0, 0);
        oacc[qg][0] = __builtin_amdgcn_mfma_f32_16x16x32_bf16(pf8, vfc[c][0], oacc[qg][0], 0, 0, 0);
        oacc[qg][1] = __builtin_amdgcn_mfma_f32_16x16x32_bf16(pf8, vfc[c][1], oacc[qg][1], 0, 0, 0);
      }
    if (has_next) {
#pragma unroll
      for (int t = 0; t < 4; t++) kfc[t] = kfn[t];
#pragma unroll
      for (int c = 0; c < 2; c++) {
        vfc[c][0] = vfn[c][0];
        vfc[c][1] = vfn[c][1];
      }
    }
  }

  int bb = bh >> 3, hh = bh & 7;
#pragma unroll
  for (int qg = 0; qg < 2; qg++)
#pragma unroll
    for (int r = 0; r < 4; r++) {
      float linv = 1.0f / lacc[qg][r];
      int row = qr0 + qg * 16 + quad * 4 + r;
      bf16_t* op = OB + ((size_t)(bb * SEQ + row)) * DIM + hh * DK;
      op[n16] = (bf16_t)(oacc[qg][0][r] * linv);
      op[16 + n16] = (bf16_t)(oacc[qg][1][r] * linv);
    }
}

// ---------------------------------------------------------------------------
extern "C" void kernel_launch(void* const* d_in, const int* in_sizes, int n_in,
                              void* d_out, int out_size, void* d_ws, size_t ws_size,
                              hipStream_t stream) {
  const float* x     = (const float*)d_in[0];
  const float* ln0_s = (const float*)d_in[1];
  const float* ln0_b = (const float*)d_in[2];
  const float* ln1_s = (const float*)d_in[3];
  const float* ln1_b = (const float*)d_in[4];
  const float* ln2_s = (const float*)d_in[5];
  const float* ln2_b = (const float*)d_in[6];
  const float* wq = (const float*)d_in[7];
  const float* bq = (const float*)d_in[8];
  const float* wk = (const float*)d_in[9];
  const float* bk = (const float*)d_in[10];
  const float* wv = (const float*)d_in[11];
  const float* bv = (const float*)d_in[12];
  const float* wo = (const float*)d_in[13];
  const float* bo = (const float*)d_in[14];
  const float* w1 = (const float*)d_in[15];
  const float* b1 = (const float*)d_in[16];
  const float* w2 = (const float*)d_in[17];
  const float* b2 = (const float*)d_in[18];

  float* out = (float*)d_out;  // h (fp32 residual stream) lives here
  const size_t ACT = (size_t)8192 * DIM;  // 2,097,152

  bf16_t* wsb = (bf16_t*)d_ws;
  bf16_t* x2b = wsb;                 // ACT
  bf16_t* obf = x2b + ACT;           // ACT
  bf16_t* qbf = obf + ACT;           // ACT
  bf16_t* kbf = qbf + ACT;           // ACT
  bf16_t* vbf = kbf + ACT;           // ACT (transposed [B,H,DK,S])
  bf16_t* h1b = vbf + ACT;           // 2*ACT (8192 x 512)
  bf16_t* WqT = h1b + 2 * ACT;       // 4 x 65536
  bf16_t* WkT = WqT + 4 * 65536;
  bf16_t* WvT = WkT + 4 * 65536;
  bf16_t* WoT = WvT + 4 * 65536;
  bf16_t* W1T = WoT + 4 * 65536;     // 4 x 131072
  bf16_t* W2T = W1T + 4 * 131072;    // 4 x 131072

  dim3 blk(256);
  dim3 blkF(128);
  dim3 gLN(2048);
  dim3 gG256(2, 64);   // 128x128 tiles over [8192 x 256]
  dim3 gG512(4, 64);   // 128x128 tiles over [8192 x 512]
  dim3 gQKV(6, 64);    // 3 weights x 2 n-blocks
  dim3 gAtt(32, 32);

  wtrans_all_kernel<<<dim3(512), blk, 0, stream>>>(wq, wk, wv, wo, w1, w2,
                                                   WqT, WkT, WvT, WoT, W1T, W2T);

  // h = LN(x, ln0) -> fp32 d_out
  ln_kernel<0><<<gLN, blk, 0, stream>>>(x, ln0_s, ln0_b, out, nullptr);

  for (int l = 0; l < 4; l++) {
    bf16_t* WqTl = WqT + (size_t)l * 65536;
    bf16_t* WkTl = WkT + (size_t)l * 65536;
    bf16_t* WvTl = WvT + (size_t)l * 65536;
    bf16_t* WoTl = WoT + (size_t)l * 65536;
    bf16_t* W1Tl = W1T + (size_t)l * 131072;
    bf16_t* W2Tl = W2T + (size_t)l * 131072;

    // x2 = LN(h, ln1) -> bf16
    ln_kernel<1><<<gLN, blk, 0, stream>>>(out, ln1_s + l * DIM, ln1_b + l * DIM, nullptr, x2b);
    // fused q,k,v projections (128x128 pipelined GEMM)
    qkv9_kernel<<<gQKV, blk, 0, stream>>>(x2b, WqTl, WkTl, WvTl,
                                          bq + l * DIM, bk + l * DIM, bv + l * DIM,
                                          qbf, kbf, vbf);
    // attention
    flash7_kernel<<<gAtt, blkF, 0, stream>>>(qbf, kbf, vbf, obf);
    // h = h + o @ Wo + bo
    gemm9_kernel<0, 256, 256><<<gG256, blk, 0, stream>>>(obf, WoTl, bo + l * DIM, out, out, nullptr);
    // x2 = LN(h, ln2) -> bf16
    ln_kernel<1><<<gLN, blk, 0, stream>>>(out, ln2_s + l * DIM, ln2_b + l * DIM, nullptr, x2b);
    // h1 = relu(x2 @ W1 + b1) -> bf16
    gemm9_kernel<1, 512, 256><<<gG512, blk, 0, stream>>>(x2b, W1Tl, b1 + l * FF, nullptr, nullptr, h1b);
    // h = h + h1 @ W2 + b2
    gemm9_kernel<0, 256, 512><<<gG256, blk, 0, stream>>>(h1b, W2Tl, b2 + l * DIM, out, out, nullptr);
  }
}

// Round 10
// 450.688 us; speedup vs baseline: 1.0398x; 1.0398x over previous
//
#include <hip/hip_runtime.h>
#include <hip/hip_bf16.h>
#include <math.h>

// Problem constants: B=4, S=2048, D=256, H=8, DK=32, L=4, FF=512
#define SEQ 2048
#define DIM 256
#define NH 8
#define DK 32
#define FF 512

typedef __bf16 bf16_t;
typedef bf16_t bf16x8 __attribute__((ext_vector_type(8)));
typedef bf16_t bf16x4 __attribute__((ext_vector_type(4)));
typedef float f32x4 __attribute__((ext_vector_type(4)));

// Q pre-scaled by (1/sqrt(DK)) * log2(e); softmax exp becomes v_exp_f32 (2^x).
#define QK_SCALE_LOG2 0.25503226632462494f
#if __has_builtin(__builtin_amdgcn_exp2f)
#define FAST_EXP2(x) __builtin_amdgcn_exp2f(x)
#else
#define FAST_EXP2(x) __expf((x) * 0.6931471805599453f)
#endif

// ---------------------------------------------------------------------------
// Double LayerNorm (start of network): h = LN(x,ln0); x2 = LN(h,ln1[0]).
// One wave per row; writes h fp32 and x2 bf16 in one pass.
// ---------------------------------------------------------------------------
__global__ __launch_bounds__(256) void ln_double_kernel(
    const float* __restrict__ x, const float* __restrict__ s0,
    const float* __restrict__ b0, const float* __restrict__ s1,
    const float* __restrict__ b1, float* __restrict__ outf,
    bf16_t* __restrict__ outb) {
  int wave = threadIdx.x >> 6;
  int lane = threadIdx.x & 63;
  int row = blockIdx.x * 4 + wave;
  float4 xv = *(const float4*)(x + (size_t)row * DIM + lane * 4);
  float sum = xv.x + xv.y + xv.z + xv.w;
  float sq = xv.x * xv.x + xv.y * xv.y + xv.z * xv.z + xv.w * xv.w;
#pragma unroll
  for (int off = 1; off < 64; off <<= 1) {
    sum += __shfl_xor(sum, off);
    sq += __shfl_xor(sq, off);
  }
  float mean = sum * (1.0f / 256.0f);
  float var = sq * (1.0f / 256.0f) - mean * mean;
  float inv = rsqrtf(var + 1e-5f);
  float4 sv = *(const float4*)(s0 + lane * 4);
  float4 bv = *(const float4*)(b0 + lane * 4);
  float4 h;
  h.x = (xv.x - mean) * inv * sv.x + bv.x;
  h.y = (xv.y - mean) * inv * sv.y + bv.y;
  h.z = (xv.z - mean) * inv * sv.z + bv.z;
  h.w = (xv.w - mean) * inv * sv.w + bv.w;
  *(float4*)(outf + (size_t)row * DIM + lane * 4) = h;
  // second LN on h
  float sum2 = h.x + h.y + h.z + h.w;
  float sq2 = h.x * h.x + h.y * h.y + h.z * h.z + h.w * h.w;
#pragma unroll
  for (int off = 1; off < 64; off <<= 1) {
    sum2 += __shfl_xor(sum2, off);
    sq2 += __shfl_xor(sq2, off);
  }
  float mean2 = sum2 * (1.0f / 256.0f);
  float var2 = sq2 * (1.0f / 256.0f) - mean2 * mean2;
  float inv2 = rsqrtf(var2 + 1e-5f);
  float4 s1v = *(const float4*)(s1 + lane * 4);
  float4 b1v = *(const float4*)(b1 + lane * 4);
  bf16x4 ob = {(bf16_t)((h.x - mean2) * inv2 * s1v.x + b1v.x),
               (bf16_t)((h.y - mean2) * inv2 * s1v.y + b1v.y),
               (bf16_t)((h.z - mean2) * inv2 * s1v.z + b1v.z),
               (bf16_t)((h.w - mean2) * inv2 * s1v.w + b1v.w)};
  *(bf16x4*)(outb + (size_t)row * DIM + lane * 4) = ob;
}

// ---------------------------------------------------------------------------
// All-weights transpose+convert in ONE dispatch (512 blocks).
// in f32 [K][N] -> out bf16 [N][K].
// ---------------------------------------------------------------------------
__global__ __launch_bounds__(256) void wtrans_all_kernel(
    const float* __restrict__ wq, const float* __restrict__ wk,
    const float* __restrict__ wv, const float* __restrict__ wo,
    const float* __restrict__ w1, const float* __restrict__ w2,
    bf16_t* __restrict__ WqT, bf16_t* __restrict__ WkT,
    bf16_t* __restrict__ WvT, bf16_t* __restrict__ WoT,
    bf16_t* __restrict__ W1T, bf16_t* __restrict__ W2T) {
  __shared__ float tile[64][65];
  int idx = blockIdx.x;
  int layer = idx >> 7;
  int r = idx & 127;
  const float* src;
  bf16_t* dst;
  int N, k0, n0;
  if (r < 64) {
    int which = r >> 4, t = r & 15;
    N = 256;
    k0 = (t & 3) * 64;
    n0 = (t >> 2) * 64;
    src = (which == 0 ? wq : which == 1 ? wk : which == 2 ? wv : wo) + (size_t)layer * 65536;
    dst = (which == 0 ? WqT : which == 1 ? WkT : which == 2 ? WvT : WoT) + (size_t)layer * 65536;
  } else if (r < 96) {
    int t = r - 64;
    N = 512;
    k0 = (t & 3) * 64;
    n0 = (t >> 2) * 64;
    src = w1 + (size_t)layer * 131072;
    dst = W1T + (size_t)layer * 131072;
  } else {
    int t = r - 96;
    N = 256;
    k0 = (t & 7) * 64;
    n0 = (t >> 3) * 64;
    src = w2 + (size_t)layer * 131072;
    dst = W2T + (size_t)layer * 131072;
  }
  int K = (r >= 96) ? 512 : 256;

  int tr = threadIdx.x >> 4;
  int tc4 = (threadIdx.x & 15) * 4;
#pragma unroll
  for (int i = 0; i < 4; i++) {
    int kl = i * 16 + tr;
    float4 v = *(const float4*)(src + (size_t)(k0 + kl) * N + n0 + tc4);
    tile[kl][tc4 + 0] = v.x; tile[kl][tc4 + 1] = v.y;
    tile[kl][tc4 + 2] = v.z; tile[kl][tc4 + 3] = v.w;
  }
  __syncthreads();
#pragma unroll
  for (int i = 0; i < 4; i++) {
    int nl = i * 16 + tr;
    bf16x4 o = {(bf16_t)tile[tc4 + 0][nl], (bf16_t)tile[tc4 + 1][nl],
                (bf16_t)tile[tc4 + 2][nl], (bf16_t)tile[tc4 + 3][nl]};
    *(bf16x4*)(dst + (size_t)(n0 + nl) * K + k0 + tc4) = o;
  }
}

// ---------------------------------------------------------------------------
// 128x128 GEMM core (unchanged from R8) used for qkv and FFN1.
// ---------------------------------------------------------------------------
__device__ __forceinline__ void stage128(const bf16_t* __restrict__ src,
                                         bf16_t* dst, int tid, int ldk, int k0) {
#pragma unroll
  for (int u = 0; u < 4; u++) {
    int i = u * 256 + tid;
    int m = i >> 3, cd = i & 7, cs = cd ^ (m & 7);
    const bf16_t* g = src + (size_t)m * ldk + k0 + cs * 8;
    __builtin_amdgcn_global_load_lds(
        (const __attribute__((address_space(1))) unsigned int*)g,
        (__attribute__((address_space(3))) unsigned int*)(dst + i * 8),
        16, 0, 0);
  }
}

__device__ __forceinline__ void compute128(const bf16_t* As, const bf16_t* Bs,
                                           int wr, int wc, int n16, int quad,
                                           f32x4 (&acc)[4][4]) {
#pragma unroll
  for (int ks = 0; ks < 2; ks++) {
    bf16x8 af[4], bf[4];
#pragma unroll
    for (int mt = 0; mt < 4; mt++) {
      int row = wr * 64 + mt * 16 + n16;
      int cd = (ks * 4 + quad) ^ (row & 7);
      af[mt] = *(const bf16x8*)(As + row * 64 + cd * 8);
    }
#pragma unroll
    for (int nt = 0; nt < 4; nt++) {
      int row = wc * 64 + nt * 16 + n16;
      int cd = (ks * 4 + quad) ^ (row & 7);
      bf[nt] = *(const bf16x8*)(Bs + row * 64 + cd * 8);
    }
#pragma unroll
    for (int mt = 0; mt < 4; mt++)
#pragma unroll
      for (int nt = 0; nt < 4; nt++)
        acc[mt][nt] = __builtin_amdgcn_mfma_f32_16x16x32_bf16(
            af[mt], bf[nt], acc[mt][nt], 0, 0, 0);
  }
}

template <int K>
__device__ __forceinline__ void gemm9_body(
    const bf16_t* __restrict__ A, const bf16_t* __restrict__ BT,
    int m0, int n0, int tid, bf16_t* As, bf16_t* Bs, f32x4 (&acc)[4][4]) {
  int lane = tid & 63;
  int n16 = lane & 15, quad = lane >> 4;
  int w = tid >> 6;
  int wr = w >> 1, wc = w & 1;
  const bf16_t* Arow = A + (size_t)m0 * K;
  const bf16_t* Brow = BT + (size_t)n0 * K;

  stage128(Arow, As, tid, K, 0);
  stage128(Brow, Bs, tid, K, 0);

  const int steps = K / 64;
#pragma unroll
  for (int s = 0; s < steps; s++) {
    int buf = s & 1;
    if (s + 1 < steps) {
      stage128(Arow, As + (buf ^ 1) * 8192, tid, K, (s + 1) * 64);
      stage128(Brow, Bs + (buf ^ 1) * 8192, tid, K, (s + 1) * 64);
    }
    __syncthreads();
    compute128(As + buf * 8192, Bs + buf * 8192, wr, wc, n16, quad, acc);
    if (s + 2 < steps) __syncthreads();
  }
}

// ---------------------------------------------------------------------------
// FFN1 GEMM (128x128): h1 = bf16(relu(x2 @ W1 + b1)).
// ---------------------------------------------------------------------------
template <int N, int K>
__global__ __launch_bounds__(256) void gemm_relu_kernel(
    const bf16_t* __restrict__ A, const bf16_t* __restrict__ BT,
    const float* __restrict__ bias, bf16_t* __restrict__ outb) {
  __shared__ __align__(16) bf16_t As[2 * 8192];
  __shared__ __align__(16) bf16_t Bs[2 * 8192];
  int tid = threadIdx.x;
  int lane = tid & 63;
  int n16 = lane & 15, quad = lane >> 4;
  int w = tid >> 6;
  int wr = w >> 1, wc = w & 1;
  int m0 = blockIdx.y * 128, n0 = blockIdx.x * 128;
  f32x4 acc[4][4] = {};
  gemm9_body<K>(A, BT, m0, n0, tid, As, Bs, acc);

#pragma unroll
  for (int nt = 0; nt < 4; nt++) {
    int n = n0 + wc * 64 + nt * 16 + n16;
    float bv = bias[n];
#pragma unroll
    for (int mt = 0; mt < 4; mt++)
#pragma unroll
      for (int r = 0; r < 4; r++) {
        int m = m0 + wr * 64 + mt * 16 + quad * 4 + r;
        outb[(size_t)m * N + n] = (bf16_t)fmaxf(acc[mt][nt][r] + bv, 0.0f);
      }
  }
}

// ---------------------------------------------------------------------------
// Fused QKV projection on the 128x128 body (unchanged from R8): grid (6, 64).
// ---------------------------------------------------------------------------
__global__ __launch_bounds__(256) void qkv9_kernel(
    const bf16_t* __restrict__ A,
    const bf16_t* __restrict__ WqT, const bf16_t* __restrict__ WkT,
    const bf16_t* __restrict__ WvT,
    const float* __restrict__ bq, const float* __restrict__ bk,
    const float* __restrict__ bv,
    bf16_t* __restrict__ qo, bf16_t* __restrict__ ko,
    bf16_t* __restrict__ vo) {
  __shared__ __align__(16) bf16_t As[2 * 8192];
  __shared__ __align__(16) bf16_t Bs[2 * 8192];
  int which = blockIdx.x >> 1;
  int nblk = blockIdx.x & 1;
  const bf16_t* BT = (which == 0) ? WqT : (which == 1) ? WkT : WvT;
  const float* bias = (which == 0) ? bq : (which == 1) ? bk : bv;

  int tid = threadIdx.x;
  int lane = tid & 63;
  int n16 = lane & 15, quad = lane >> 4;
  int w = tid >> 6;
  int wr = w >> 1, wc = w & 1;
  int m0 = blockIdx.y * 128, n0 = nblk * 128;
  f32x4 acc[4][4] = {};
  gemm9_body<256>(A, BT, m0, n0, tid, As, Bs, acc);

#pragma unroll
  for (int nt = 0; nt < 4; nt++) {
    int n = n0 + wc * 64 + nt * 16 + n16;
    float bv_ = bias[n];
    int hh = n >> 5, dk = n & 31;
#pragma unroll
    for (int mt = 0; mt < 4; mt++) {
      if (which == 2) {
        int s0 = m0 + wr * 64 + mt * 16 + quad * 4;
        int bb = s0 >> 11, ss0 = s0 & 2047;
        bf16x4 o;
#pragma unroll
        for (int r = 0; r < 4; r++) o[r] = (bf16_t)(acc[mt][nt][r] + bv_);
        *(bf16x4*)(vo + ((size_t)(bb * NH + hh) * DK + dk) * SEQ + ss0) = o;
      } else {
        bf16_t* dst = (which == 0) ? qo : ko;
        float sc = (which == 0) ? QK_SCALE_LOG2 : 1.0f;
#pragma unroll
        for (int r = 0; r < 4; r++) {
          int m = m0 + wr * 64 + mt * 16 + quad * 4 + r;
          int bb = m >> 11, ss = m & 2047;
          dst[((size_t)(bb * NH + hh) * SEQ + ss) * DK + dk] =
              (bf16_t)((acc[mt][nt][r] + bv_) * sc);
        }
      }
    }
  }
}

// ---------------------------------------------------------------------------
// Residual GEMM with FUSED LayerNorm epilogue. Block tile: 32 rows x ALL 256
// cols (full rows in-block -> LN stats computable). 4 waves, wave w owns cols
// [w*64, w*64+64), wave tile 32x64 = 2x4 MFMA accs. BK=64 double-buffered
// global_load_lds staging (XOR swizzle). Epilogue: h = resid + val (fp32 to
// outf) and, if LNOUT, x2 = LN(h) -> bf16 outb (stats via shuffle + LDS).
// grid = 256 blocks (M/32).
// ---------------------------------------------------------------------------
template <int K, int LNOUT>
__global__ __launch_bounds__(256) void gemm_ln_kernel(
    const bf16_t* __restrict__ A, const bf16_t* __restrict__ BT,
    const float* __restrict__ bias, const float* __restrict__ resid,
    float* __restrict__ outf, const float* __restrict__ ls,
    const float* __restrict__ lb, bf16_t* __restrict__ outb) {
  __shared__ __align__(16) bf16_t As[2 * 2048];   //  32 x 64 x 2 bufs
  __shared__ __align__(16) bf16_t Bs[2 * 16384];  // 256 x 64 x 2 bufs
  __shared__ float2 stats[4][32];
  int tid = threadIdx.x;
  int lane = tid & 63;
  int n16 = lane & 15, quad = lane >> 4;
  int w = tid >> 6;
  int m0 = blockIdx.x * 32;

  const bf16_t* Arow = A + (size_t)m0 * K;
  f32x4 acc[2][4] = {};

  // initial stage (buf 0)
  {
    int i = tid;
    int m = i >> 3, cd = i & 7, cs = cd ^ (m & 7);
    __builtin_amdgcn_global_load_lds(
        (const __attribute__((address_space(1))) unsigned int*)(Arow + (size_t)m * K + cs * 8),
        (__attribute__((address_space(3))) unsigned int*)(As + i * 8), 16, 0, 0);
#pragma unroll
    for (int u = 0; u < 8; u++) {
      int j = u * 256 + tid;
      int mb = j >> 3, cdb = j & 7, csb = cdb ^ (mb & 7);
      __builtin_amdgcn_global_load_lds(
          (const __attribute__((address_space(1))) unsigned int*)(BT + (size_t)mb * K + csb * 8),
          (__attribute__((address_space(3))) unsigned int*)(Bs + j * 8), 16, 0, 0);
    }
  }

  const int steps = K / 64;
#pragma unroll
  for (int s = 0; s < steps; s++) {
    int buf = s & 1;
    if (s + 1 < steps) {
      int k0 = (s + 1) * 64;
      int i = tid;
      int m = i >> 3, cd = i & 7, cs = cd ^ (m & 7);
      __builtin_amdgcn_global_load_lds(
          (const __attribute__((address_space(1))) unsigned int*)(Arow + (size_t)m * K + k0 + cs * 8),
          (__attribute__((address_space(3))) unsigned int*)(As + (buf ^ 1) * 2048 + i * 8), 16, 0, 0);
#pragma unroll
      for (int u = 0; u < 8; u++) {
        int j = u * 256 + tid;
        int mb = j >> 3, cdb = j & 7, csb = cdb ^ (mb & 7);
        __builtin_amdgcn_global_load_lds(
            (const __attribute__((address_space(1))) unsigned int*)(BT + (size_t)mb * K + k0 + csb * 8),
            (__attribute__((address_space(3))) unsigned int*)(Bs + (buf ^ 1) * 16384 + j * 8), 16, 0, 0);
      }
    }
    __syncthreads();
    const bf16_t* a = As + buf * 2048;
    const bf16_t* b = Bs + buf * 16384;
#pragma unroll
    for (int ks = 0; ks < 2; ks++) {
      bf16x8 af[2], bfv[4];
#pragma unroll
      for (int mt = 0; mt < 2; mt++) {
        int row = mt * 16 + n16;
        int cd = (ks * 4 + quad) ^ (row & 7);
        af[mt] = *(const bf16x8*)(a + row * 64 + cd * 8);
      }
#pragma unroll
      for (int nt = 0; nt < 4; nt++) {
        int row = w * 64 + nt * 16 + n16;
        int cd = (ks * 4 + quad) ^ (row & 7);
        bfv[nt] = *(const bf16x8*)(b + row * 64 + cd * 8);
      }
#pragma unroll
      for (int mt = 0; mt < 2; mt++)
#pragma unroll
        for (int nt = 0; nt < 4; nt++)
          acc[mt][nt] = __builtin_amdgcn_mfma_f32_16x16x32_bf16(
              af[mt], bfv[nt], acc[mt][nt], 0, 0, 0);
    }
    if (s + 2 < steps) __syncthreads();
  }

  // epilogue: h = resid + val (store fp32), stats, optional LN -> bf16
  float rsum[2][4], rsq[2][4];  // per (mt, r) partial over this lane's 4 cols
#pragma unroll
  for (int mt = 0; mt < 2; mt++)
#pragma unroll
    for (int r = 0; r < 4; r++) { rsum[mt][r] = 0.f; rsq[mt][r] = 0.f; }

#pragma unroll
  for (int nt = 0; nt < 4; nt++) {
    int n = w * 64 + nt * 16 + n16;
    float bv = bias[n];
#pragma unroll
    for (int mt = 0; mt < 2; mt++)
#pragma unroll
      for (int r = 0; r < 4; r++) {
        int m = m0 + mt * 16 + quad * 4 + r;
        size_t idx = (size_t)m * DIM + n;
        float hv = resid[idx] + acc[mt][nt][r] + bv;
        outf[idx] = hv;
        acc[mt][nt][r] = hv;  // keep for LN
        rsum[mt][r] += hv;
        rsq[mt][r] += hv * hv;
      }
  }

  if (LNOUT) {
    // reduce across the 16 n16 lanes (same quad): rows' sums over wave's 64 cols
#pragma unroll
    for (int mt = 0; mt < 2; mt++)
#pragma unroll
      for (int r = 0; r < 4; r++) {
        float s_ = rsum[mt][r], q_ = rsq[mt][r];
#pragma unroll
        for (int off = 1; off < 16; off <<= 1) {
          s_ += __shfl_xor(s_, off);
          q_ += __shfl_xor(q_, off);
        }
        rsum[mt][r] = s_;
        rsq[mt][r] = q_;
      }
    if (n16 == 0) {
#pragma unroll
      for (int mt = 0; mt < 2; mt++)
#pragma unroll
        for (int r = 0; r < 4; r++)
          stats[w][mt * 16 + quad * 4 + r] = make_float2(rsum[mt][r], rsq[mt][r]);
    }
    __syncthreads();
#pragma unroll
    for (int mt = 0; mt < 2; mt++)
#pragma unroll
      for (int r = 0; r < 4; r++) {
        int lr = mt * 16 + quad * 4 + r;
        float2 t0 = stats[0][lr], t1 = stats[1][lr], t2 = stats[2][lr], t3 = stats[3][lr];
        float tot = t0.x + t1.x + t2.x + t3.x;
        float totq = t0.y + t1.y + t2.y + t3.y;
        float mean = tot * (1.0f / 256.0f);
        float var = totq * (1.0f / 256.0f) - mean * mean;
        rsum[mt][r] = mean;
        rsq[mt][r] = rsqrtf(var + 1e-5f);
      }
#pragma unroll
    for (int nt = 0; nt < 4; nt++) {
      int n = w * 64 + nt * 16 + n16;
      float sv = ls[n], bv = lb[n];
#pragma unroll
      for (int mt = 0; mt < 2; mt++)
#pragma unroll
        for (int r = 0; r < 4; r++) {
          int m = m0 + mt * 16 + quad * 4 + r;
          float x2 = (acc[mt][nt][r] - rsum[mt][r]) * rsq[mt][r] * sv + bv;
          outb[(size_t)m * DIM + n] = (bf16_t)x2;
        }
    }
  }
}

// ---------------------------------------------------------------------------
// Flash attention v7 (unchanged): 32 q/wave, S^T trick, ones-MFMA row-sums,
// double-buffered P LDS, register K/V prefetch. grid (32,32), 128 threads.
// ---------------------------------------------------------------------------
__global__ __launch_bounds__(128) void flash7_kernel(
    const bf16_t* __restrict__ Q, const bf16_t* __restrict__ K,
    const bf16_t* __restrict__ VT, bf16_t* __restrict__ OB) {
  __shared__ __align__(16) bf16_t Plds[2][2][32][72];
  int bh = blockIdx.x;
  int q0 = blockIdx.y * 64;
  int w = threadIdx.x >> 6;
  int lane = threadIdx.x & 63;
  int n16 = lane & 15;
  int quad = lane >> 4;

  const bf16_t* Qb = Q + (size_t)bh * SEQ * DK;
  const bf16_t* Kb = K + (size_t)bh * SEQ * DK;
  const bf16_t* Vb = VT + (size_t)bh * DK * SEQ;
  int qr0 = q0 + w * 32;

  bf16x8 qfrag[2];
#pragma unroll
  for (int qg = 0; qg < 2; qg++)
    qfrag[qg] = *(const bf16x8*)(Qb + (size_t)(qr0 + qg * 16 + n16) * DK + quad * 8);

  bf16_t one = (bf16_t)1.0f;
  bf16x8 ones = {one, one, one, one, one, one, one, one};

  f32x4 oacc[2][2] = {};
  f32x4 lacc[2] = {};

  bf16x8 kfc[4], vfc[2][2];
#pragma unroll
  for (int t = 0; t < 4; t++)
    kfc[t] = *(const bf16x8*)(Kb + (size_t)(t * 16 + n16) * DK + quad * 8);
#pragma unroll
  for (int c = 0; c < 2; c++) {
    vfc[c][0] = *(const bf16x8*)(Vb + (size_t)n16 * SEQ + c * 32 + quad * 8);
    vfc[c][1] = *(const bf16x8*)(Vb + (size_t)(16 + n16) * SEQ + c * 32 + quad * 8);
  }

#pragma unroll 2
  for (int kb0 = 0; kb0 < SEQ; kb0 += 64) {
    int buf = (kb0 >> 6) & 1;
    int nb = kb0 + 64;
    bool has_next = nb < SEQ;
    bf16x8 kfn[4], vfn[2][2];
    if (has_next) {
#pragma unroll
      for (int t = 0; t < 4; t++)
        kfn[t] = *(const bf16x8*)(Kb + (size_t)(nb + t * 16 + n16) * DK + quad * 8);
#pragma unroll
      for (int c = 0; c < 2; c++) {
        vfn[c][0] = *(const bf16x8*)(Vb + (size_t)n16 * SEQ + nb + c * 32 + quad * 8);
        vfn[c][1] = *(const bf16x8*)(Vb + (size_t)(16 + n16) * SEQ + nb + c * 32 + quad * 8);
      }
    }
#pragma unroll
    for (int qg = 0; qg < 2; qg++) {
#pragma unroll
      for (int t = 0; t < 4; t++) {
        f32x4 sc = __builtin_amdgcn_mfma_f32_16x16x32_bf16(
            kfc[t], qfrag[qg], (f32x4){0.f, 0.f, 0.f, 0.f}, 0, 0, 0);
        bf16x4 pf;
#pragma unroll
        for (int r = 0; r < 4; r++) pf[r] = (bf16_t)FAST_EXP2(sc[r]);
        *(bf16x4*)&Plds[buf][w][qg * 16 + n16][t * 16 + quad * 4] = pf;
      }
    }
#pragma unroll
    for (int qg = 0; qg < 2; qg++)
#pragma unroll
      for (int c = 0; c < 2; c++) {
        bf16x8 pf8 = *(const bf16x8*)&Plds[buf][w][qg * 16 + n16][c * 32 + quad * 8];
        lacc[qg] = __builtin_amdgcn_mfma_f32_16x16x32_bf16(pf8, ones, lacc[qg], 0, 0, 0);
        oacc[qg][0] = __builtin_amdgcn_mfma_f32_16x16x32_bf16(pf8, vfc[c][0], oacc[qg][0], 0, 0, 0);
        oacc[qg][1] = __builtin_amdgcn_mfma_f32_16x16x32_bf16(pf8, vfc[c][1], oacc[qg][1], 0, 0, 0);
      }
    if (has_next) {
#pragma unroll
      for (int t = 0; t < 4; t++) kfc[t] = kfn[t];
#pragma unroll
      for (int c = 0; c < 2; c++) {
        vfc[c][0] = vfn[c][0];
        vfc[c][1] = vfn[c][1];
      }
    }
  }

  int bb = bh >> 3, hh = bh & 7;
#pragma unroll
  for (int qg = 0; qg < 2; qg++)
#pragma unroll
    for (int r = 0; r < 4; r++) {
      float linv = 1.0f / lacc[qg][r];
      int row = qr0 + qg * 16 + quad * 4 + r;
      bf16_t* op = OB + ((size_t)(bb * SEQ + row)) * DIM + hh * DK;
      op[n16] = (bf16_t)(oacc[qg][0][r] * linv);
      op[16 + n16] = (bf16_t)(oacc[qg][1][r] * linv);
    }
}

// ---------------------------------------------------------------------------
extern "C" void kernel_launch(void* const* d_in, const int* in_sizes, int n_in,
                              void* d_out, int out_size, void* d_ws, size_t ws_size,
                              hipStream_t stream) {
  const float* x     = (const float*)d_in[0];
  const float* ln0_s = (const float*)d_in[1];
  const float* ln0_b = (const float*)d_in[2];
  const float* ln1_s = (const float*)d_in[3];
  const float* ln1_b = (const float*)d_in[4];
  const float* ln2_s = (const float*)d_in[5];
  const float* ln2_b = (const float*)d_in[6];
  const float* wq = (const float*)d_in[7];
  const float* bq = (const float*)d_in[8];
  const float* wk = (const float*)d_in[9];
  const float* bk = (const float*)d_in[10];
  const float* wv = (const float*)d_in[11];
  const float* bv = (const float*)d_in[12];
  const float* wo = (const float*)d_in[13];
  const float* bo = (const float*)d_in[14];
  const float* w1 = (const float*)d_in[15];
  const float* b1 = (const float*)d_in[16];
  const float* w2 = (const float*)d_in[17];
  const float* b2 = (const float*)d_in[18];

  float* out = (float*)d_out;  // h (fp32 residual stream) lives here
  const size_t ACT = (size_t)8192 * DIM;  // 2,097,152

  bf16_t* wsb = (bf16_t*)d_ws;
  bf16_t* x2b = wsb;                 // ACT
  bf16_t* obf = x2b + ACT;           // ACT
  bf16_t* qbf = obf + ACT;           // ACT
  bf16_t* kbf = qbf + ACT;           // ACT
  bf16_t* vbf = kbf + ACT;           // ACT (transposed [B,H,DK,S])
  bf16_t* h1b = vbf + ACT;           // 2*ACT (8192 x 512)
  bf16_t* WqT = h1b + 2 * ACT;       // 4 x 65536
  bf16_t* WkT = WqT + 4 * 65536;
  bf16_t* WvT = WkT + 4 * 65536;
  bf16_t* WoT = WvT + 4 * 65536;
  bf16_t* W1T = WoT + 4 * 65536;     // 4 x 131072
  bf16_t* W2T = W1T + 4 * 131072;    // 4 x 131072

  dim3 blk(256);
  dim3 blkF(128);
  dim3 gLN(2048);
  dim3 gGLN(256);      // 32-row residual+LN GEMM blocks
  dim3 gG512(4, 64);   // FFN1 128x128 tiles
  dim3 gQKV(6, 64);
  dim3 gAtt(32, 32);

  wtrans_all_kernel<<<dim3(512), blk, 0, stream>>>(wq, wk, wv, wo, w1, w2,
                                                   WqT, WkT, WvT, WoT, W1T, W2T);

  // h = LN(x, ln0); x2 = LN(h, ln1[0])
  ln_double_kernel<<<gLN, blk, 0, stream>>>(x, ln0_s, ln0_b, ln1_s, ln1_b, out, x2b);

  for (int l = 0; l < 4; l++) {
    bf16_t* WqTl = WqT + (size_t)l * 65536;
    bf16_t* WkTl = WkT + (size_t)l * 65536;
    bf16_t* WvTl = WvT + (size_t)l * 65536;
    bf16_t* WoTl = WoT + (size_t)l * 65536;
    bf16_t* W1Tl = W1T + (size_t)l * 131072;
    bf16_t* W2Tl = W2T + (size_t)l * 131072;

    // fused q,k,v projections
    qkv9_kernel<<<gQKV, blk, 0, stream>>>(x2b, WqTl, WkTl, WvTl,
                                          bq + l * DIM, bk + l * DIM, bv + l * DIM,
                                          qbf, kbf, vbf);
    // attention
    flash7_kernel<<<gAtt, blkF, 0, stream>>>(qbf, kbf, vbf, obf);
    // h = h + o @ Wo + bo;  x2 = LN(h, ln2)   [fused]
    gemm_ln_kernel<256, 1><<<gGLN, blk, 0, stream>>>(
        obf, WoTl, bo + l * DIM, out, out, ln2_s + l * DIM, ln2_b + l * DIM, x2b);
    // h1 = relu(x2 @ W1 + b1)
    gemm_relu_kernel<512, 256><<<gG512, blk, 0, stream>>>(x2b, W1Tl, b1 + l * FF, h1b);
    // h = h + h1 @ W2 + b2;  x2 = LN(h, ln1[l+1])  [fused, except last layer]
    if (l < 3) {
      gemm_ln_kernel<512, 1><<<gGLN, blk, 0, stream>>>(
          h1b, W2Tl, b2 + l * DIM, out, out, ln1_s + (l + 1) * DIM, ln1_b + (l + 1) * DIM, x2b);
    } else {
      gemm_ln_kernel<512, 0><<<gGLN, blk, 0, stream>>>(
          h1b, W2Tl, b2 + l * DIM, out, out, nullptr, nullptr, nullptr);
    }
  }
}